// Round 3
// baseline (159.551 us; speedup 1.0000x reference)
//
#include <hip/hip_runtime.h>
#include <math.h>

// Problem constants (fixed by setup_inputs): B=4096, T=512, Q=4
#define T_DIM 512
#define GAMMA_F 0.997f
#define EPS_F 1e-3f
// log2(0.997)
#define LOG2_GAMMA (-0.0043345907f)

typedef float v4f __attribute__((ext_vector_type(4)));

__device__ __forceinline__ float inv_rescale_f(float x) {
    float s = (x > 0.f) ? 1.f : ((x < 0.f) ? -1.f : 0.f);
    float sqrt_arg = 1.f + 4.f * EPS_F * (fabsf(x) + 1.f + EPS_F);
    float q = (sqrtf(sqrt_arg) - 1.f) * (1.f / (2.f * EPS_F));
    return s * (q * q - 1.f);
}

__device__ __forceinline__ float rescale_f(float x) {
    return copysignf(sqrtf(fabsf(x) + 1.f) - 1.f, x) + EPS_F * x;
}

// R6 (second resubmit — R1/R2 benches were GPU-acquisition timeouts; kernel
// has never run): latency-bound fix by construction, not by scheduler
// cooperation. The R0 version issued 22 global loads/thread and hoped
// sched_barrier(0) would keep them in flight; VGPR_Count=24 proved the
// compiler serialized them anyway (~1 outstanding load/wave -> ~2 TB/s
// Little's-law ceiling). New structure: one block = one row (512 threads),
// each thread does exactly 6 coalesced global loads (15 dest VGPRs ->
// trivially all in flight), stages pre-combined window operands
// (m*r, m*(1-d)*p, m*(1-d)) into LDS with a 4-slot zero/clamp pad, then the
// 5-tap window sum reads LDS only - no clamping or validity math in the hot
// path.
__global__ __launch_bounds__(512) void nstep_qloss_kernel(
    const float* __restrict__ cur_q,    // (B,T,4)
    const float* __restrict__ next_q,   // (B,T,4)
    const float* __restrict__ log_p,    // (B,T)
    const float* __restrict__ reward,   // (B,T,4)
    const float* __restrict__ is_done,  // (B,T)
    const float* __restrict__ mask,     // (B,T)
    float* __restrict__ out)            // (B,T,4)
{
    __shared__ v4f   s_mr [T_DIM + 4];  // m * reward           (pad: 0)
    __shared__ float s_lpv[T_DIM + 4];  // m * (1-d) * log_p    (pad: 0)
    __shared__ float s_md [T_DIM + 4];  // m * (1-d)            (pad: value at T-1)

    const int t    = threadIdx.x;
    const int base = blockIdx.x * T_DIM;      // b * T
    const int idx  = base + t;
    const int s4   = (t + 4 < T_DIM) ? t + 4 : T_DIM - 1;

    const v4f* rew4 = (const v4f*)reward;
    const v4f* nq4  = (const v4f*)next_q;
    const v4f* cq4  = (const v4f*)cur_q;
    v4f*       out4 = (v4f*)out;

    // ---- 6 coalesced global loads; few dest regs => all naturally in flight ----
    float m = mask[idx];
    float d = is_done[idx];
    float p = log_p[idx];
    v4f   r = rew4[idx];
    v4f  nq = nq4[base + s4];
    v4f  cq = cq4[idx];

    // ---- stage pre-combined operands ----
    float md = m * (1.f - d);
    s_mr [t] = m * r;
    s_lpv[t] = md * p;
    s_md [t] = md;
    if (t == T_DIM - 1) {
        v4f z; z.x = 0.f; z.y = 0.f; z.z = 0.f; z.w = 0.f;
        #pragma unroll
        for (int k = 1; k <= 4; ++k) {
            s_mr [T_DIM - 1 + k] = z;
            s_lpv[T_DIM - 1 + k] = 0.f;
            s_md [T_DIM - 1 + k] = md;   // clamp semantics for next_term
        }
    }
    __syncthreads();

    const float g1 = GAMMA_F;
    const float g2 = g1 * g1;
    const float g3 = g2 * g1;
    const float g4 = g2 * g2;

    // ---- 5-tap window entirely from LDS (conflict-free strides) ----
    v4f A0 = s_mr[t];
    v4f A1 = s_mr[t + 1];
    v4f A2 = s_mr[t + 2];
    v4f A3 = s_mr[t + 3];
    v4f A4 = s_mr[t + 4];
    float l0 = s_lpv[t];
    float l1 = s_lpv[t + 1];
    float l2 = s_lpv[t + 2];
    float l3 = s_lpv[t + 3];
    float l4 = s_lpv[t + 4];
    float md4 = s_md[t + 4];

    // reward_sum per q (q=2 has weight 0 -> skipped)
    float a0 = A0.x, a1 = A0.y, a3 = A0.w;
    a0 = fmaf(g1, A1.x, a0); a1 = fmaf(g1, A1.y, a1); a3 = fmaf(g1, A1.w, a3);
    a0 = fmaf(g2, A2.x, a0); a1 = fmaf(g2, A2.y, a1); a3 = fmaf(g2, A2.w, a3);
    a0 = fmaf(g3, A3.x, a0); a1 = fmaf(g3, A3.y, a1); a3 = fmaf(g3, A3.w, a3);
    a0 = fmaf(g4, A4.x, a0); a1 = fmaf(g4, A4.y, a1); a3 = fmaf(g4, A4.w, a3);

    // log_p window sum (q-independent)
    float Ls = l0;
    Ls = fmaf(g1, l1, Ls);
    Ls = fmaf(g2, l2, Ls);
    Ls = fmaf(g3, l3, Ls);
    Ls = fmaf(g4, l4, Ls);
    Ls *= GAMMA_F * (1.f / 3.f);        // extra gamma factor * inv_num_q

    // next_term: coeff = gamma^i (absolute index, faithful), i = s4
    float coeff = exp2f((float)s4 * LOG2_GAMMA);
    float g = coeff * md4;
    float nt0 = g * inv_rescale_f(nq.x);
    float nt1 = g * inv_rescale_f(nq.y);
    float nt3 = g * inv_rescale_f(nq.w);

    // q_w = {1, 0.5, 0, 2}; inv_qw = {1, 2, 0, 0.5}
    float tgt0 = rescale_f(a0 + nt0 + 1.0f * Ls);
    float tgt1 = rescale_f(a1 + nt1 + 2.0f * Ls);
    float tgt3 = rescale_f(a3 + nt3 + 0.5f * Ls);

    float hm = 0.5f * m;
    float e0 = cq.x - tgt0;
    float e1 = cq.y - tgt1;
    float e3 = cq.w - tgt3;
    v4f o;
    o.x = hm * e0 * e0;
    o.y = hm * 0.5f * e1 * e1;
    o.z = 0.f;                          // q_w[2] == 0
    o.w = hm * 2.0f * e3 * e3;
    out4[idx] = o;
}

extern "C" void kernel_launch(void* const* d_in, const int* in_sizes, int n_in,
                              void* d_out, int out_size, void* d_ws, size_t ws_size,
                              hipStream_t stream) {
    const float* cur_q   = (const float*)d_in[0];
    const float* next_q  = (const float*)d_in[1];
    const float* log_p   = (const float*)d_in[2];
    const float* reward  = (const float*)d_in[3];
    const float* is_done = (const float*)d_in[4];
    const float* mask    = (const float*)d_in[5];
    float* out = (float*)d_out;

    int BT = in_sizes[2];               // B*T (element count)
    int blocks = BT / T_DIM;            // one block per row; T=512 exactly
    hipLaunchKernelGGL(nstep_qloss_kernel, dim3(blocks), dim3(512), 0, stream,
                       cur_q, next_q, log_p, reward, is_done, mask, out);
}